// Round 1
// baseline (3182.144 us; speedup 1.0000x reference)
//
#include <hip/hip_runtime.h>

// Hartree-Fock SCF solver, NX=240, A_ORB=2, 500 sequential iterations.
// Strategy: single persistent workgroup (1 CU), all state in LDS.
// kin_mat and Vint are exactly Toeplitz (uniform grid) -> matvecs become
// length-240 convolutions with ~2KB of LDS-resident coefficients.
// Umf_mat is never materialized:
//   Umf@v = -delx*(wf0*(Vc@(wf0*v)) + wf1*(Vc@(wf1*v))) + (Udir+U_HO)*v
// Regular iteration: 5 fused convolutions + small vector phase (6 barriers).
// Final iteration additionally: 6 convolutions for ekin/epot + output write.

#define NXX   240
#define NPAD  256
#define CLEN  512
#define NTH   512
#define NWAVES 8
#define NGRP  2      // j-split groups over threads
#define JPER  120    // NXX / NGRP
#define NBLK  30     // JPER / 4

__device__ __forceinline__ float waveSum(float v) {
#pragma unroll
  for (int o = 32; o > 0; o >>= 1) v += __shfl_down(v, o, 64);
  return v;
}

__device__ __forceinline__ float sum8(const float* p) {
  float4 A = *(const float4*)p;
  float4 B = *(const float4*)(p + 4);
  return ((A.x + A.y) + (A.z + A.w)) + ((B.x + B.y) + (B.z + B.w));
}

struct __align__(16) Smem {
  float cK[CLEN];          // Toeplitz coeffs of kin_mat, index d+239
  float cV[CLEN];          // Toeplitz coeffs of Vint
  float uho[NPAD];
  float wfb[2][2][NPAD];   // ping-pong wavefunctions [buf][orbital][x]
  float p00[NPAD];         // wf0*wf0
  float p01[NPAD];         // wf0*wf1
  float p11[NPAD];         // wf1*wf1
  float prod[4][NPAD];     // final-iter products wf_m * new_n
  float part[NGRP][6][NPAD]; // conv partial sums per j-group
  float red1[8][NWAVES];   // 0:nrm0 1:nrm1 2:spe0 3:spe1 4:eho
  float red2[NWAVES];
  float red3[NWAVES];
  float red4[NWAVES];
  float red5[2][NWAVES];   // ekin, epot partials
};

__global__ void __launch_bounds__(NTH)
hf_kernel(const float* __restrict__ wfy0,
          const float* __restrict__ kin,
          const float* __restrict__ vnt,
          const float* __restrict__ uho_g,
          const float* __restrict__ delx_p,
          const float* __restrict__ pfac_p,
          const int*   __restrict__ iter_p,
          float* __restrict__ out)
{
  __shared__ Smem sm;
  const int t    = (int)threadIdx.x;
  const int lane = t & 63;
  const int wv   = t >> 6;
  const int i    = t & (NPAD - 1);   // output row this thread accumulates
  const int g    = t >> 8;           // j-group (0..NGRP-1)
  const float delx = delx_p[0];
  const float pfac = pfac_p[0];
  const int itermax = iter_p[0];

  // ---- one-time setup: extract Toeplitz coeffs, load vectors ----
  for (int a = t; a < CLEN; a += NTH) {
    int d = a - 239;                 // d = i - j
    float vk = 0.f, vv = 0.f;
    if (d >= 0 && d < NXX)        { vk = kin[(size_t)d * NXX]; vv = vnt[(size_t)d * NXX]; }
    else if (d < 0 && -d < NXX)   { vk = kin[-d];              vv = vnt[-d]; }
    sm.cK[a] = vk; sm.cV[a] = vv;
  }
  if (t < NPAD) {
    float u  = (t < NXX) ? uho_g[t]       : 0.f;
    float a0 = (t < NXX) ? wfy0[2 * t]     : 0.f;
    float a1 = (t < NXX) ? wfy0[2 * t + 1] : 0.f;
    sm.uho[t] = u;
    sm.wfb[0][0][t] = a0; sm.wfb[0][1][t] = a1;
    sm.wfb[1][0][t] = 0.f; sm.wfb[1][1][t] = 0.f;
    sm.p00[t] = a0 * a0; sm.p01[t] = a0 * a1; sm.p11[t] = a1 * a1;
  }
  __syncthreads();

  int cur = 0;
  for (int it = 0; it < itermax; ++it) {
    const bool last = (it == itermax - 1);
    const float* wf0 = sm.wfb[cur][0];
    const float* wf1 = sm.wfb[cur][1];
    float* nw0 = sm.wfb[cur ^ 1][0];
    float* nw1 = sm.wfb[cur ^ 1][1];

    // ===== fused 5-conv pass: kin@wf0, kin@wf1, Vc@p00, Vc@p01, Vc@p11 =====
    float a0 = 0.f, a1 = 0.f, a2 = 0.f, a3 = 0.f, a4 = 0.f;
    {
      const int jg = g * JPER;
#pragma unroll
      for (int b = 0; b < NBLK; ++b) {
        const int j0 = jg + 4 * b;
        const float4 x0 = *(const float4*)(wf0 + j0);
        const float4 x1 = *(const float4*)(wf1 + j0);
        const float4 q0 = *(const float4*)(sm.p00 + j0);
        const float4 q1 = *(const float4*)(sm.p01 + j0);
        const float4 q2 = *(const float4*)(sm.p11 + j0);
        const int base = i + 239 - j0;
        float ck, cv;
        ck = sm.cK[base    ]; cv = sm.cV[base    ];
        a0 += ck * x0.x; a1 += ck * x1.x; a2 += cv * q0.x; a3 += cv * q1.x; a4 += cv * q2.x;
        ck = sm.cK[base - 1]; cv = sm.cV[base - 1];
        a0 += ck * x0.y; a1 += ck * x1.y; a2 += cv * q0.y; a3 += cv * q1.y; a4 += cv * q2.y;
        ck = sm.cK[base - 2]; cv = sm.cV[base - 2];
        a0 += ck * x0.z; a1 += ck * x1.z; a2 += cv * q0.z; a3 += cv * q1.z; a4 += cv * q2.z;
        ck = sm.cK[base - 3]; cv = sm.cV[base - 3];
        a0 += ck * x0.w; a1 += ck * x1.w; a2 += cv * q0.w; a3 += cv * q1.w; a4 += cv * q2.w;
      }
    }
    sm.part[g][0][i] = a0; sm.part[g][1][i] = a1; sm.part[g][2][i] = a2;
    sm.part[g][3][i] = a3; sm.part[g][4][i] = a4;
    __syncthreads();

    // ===== V1: wff, wfb, batched reductions =====
    float Ut = 0.f, wb0 = 0.f, wb1 = 0.f;
    float r0 = 0.f, r1 = 0.f, r2 = 0.f, r3 = 0.f, r4 = 0.f;
    if (t < NXX) {
      float k0  = sm.part[0][0][t] + sm.part[1][0][t];
      float k1  = sm.part[0][1][t] + sm.part[1][1][t];
      float v00 = sm.part[0][2][t] + sm.part[1][2][t];
      float v01 = sm.part[0][3][t] + sm.part[1][3][t];
      float v11 = sm.part[0][4][t] + sm.part[1][4][t];
      float w0 = wf0[t], w1 = wf1[t];
      Ut = delx * (v00 + v11) + sm.uho[t];              // Udir + U_HO
      float wff0 = k0 - delx * (w0 * v00 + w1 * v01) + Ut * w0;
      float wff1 = k1 - delx * (w0 * v01 + w1 * v11) + Ut * w1;
      wb0 = w0 - pfac * wff0;
      wb1 = w1 - pfac * wff1;
      r0 = wb0 * wb0; r1 = wb1 * wb1;
      r2 = w0 * wff0; r3 = w1 * wff1;                    // spe (×delx later)
      r4 = (sm.p00[t] + sm.p11[t]) * sm.uho[t];          // eho  (×delx/2 later)
    }
    r0 = waveSum(r0); r1 = waveSum(r1); r2 = waveSum(r2);
    r3 = waveSum(r3); r4 = waveSum(r4);
    if (lane == 0) {
      sm.red1[0][wv] = r0; sm.red1[1][wv] = r1; sm.red1[2][wv] = r2;
      sm.red1[3][wv] = r3; sm.red1[4][wv] = r4;
    }
    __syncthreads();

    // ===== V2: first normalization of both orbitals =====
    float nrm0 = sum8(sm.red1[0]) * delx;
    float nrm1 = sum8(sm.red1[1]) * delx;
    float wfA = 0.f, wfBp = 0.f, q = 0.f;
    if (t < NXX) {
      wfA  = wb0 / sqrtf(nrm0);
      wfBp = wb1 / sqrtf(nrm1);
      q = wfA * wfA;
    }
    q = waveSum(q);
    if (lane == 0) sm.red2[wv] = q;
    __syncthreads();

    // ===== V3: finish orbital 0, start ortho dot =====
    float n2A = sum8(sm.red2) * delx;
    float new0 = 0.f; q = 0.f;
    if (t < NXX) {
      new0 = 0.4f * (wfA / n2A) + 0.6f * wf0[t];
      nw0[t] = new0;
      q = new0 * wfBp;
    }
    q = waveSum(q);
    if (lane == 0) sm.red3[wv] = q;
    __syncthreads();

    // ===== V4: orthogonalize orbital 1 =====
    float dB = sum8(sm.red3) * delx;
    float wfB2 = 0.f; q = 0.f;
    if (t < NXX) {
      wfB2 = wfBp - new0 * dB;
      q = wfB2 * wfB2;
    }
    q = waveSum(q);
    if (lane == 0) sm.red4[wv] = q;
    __syncthreads();

    // ===== V5: finish orbital 1, prepare next-iter products =====
    float n2B = sum8(sm.red4) * delx;
    if (t < NXX) {
      float new1 = 0.4f * (wfB2 / n2B) + 0.6f * wf1[t];
      nw1[t] = new1;
      sm.p00[t] = new0 * new0;
      sm.p01[t] = new0 * new1;
      sm.p11[t] = new1 * new1;
    }
    __syncthreads();

    // ===== final iteration: energies =====
    if (last) {
      if (t < NPAD) {
        float w0 = (t < NXX) ? wf0[t] : 0.f;
        float w1 = (t < NXX) ? wf1[t] : 0.f;
        float n0 = (t < NXX) ? nw0[t] : 0.f;
        float n1 = (t < NXX) ? nw1[t] : 0.f;
        sm.prod[0][t] = w0 * n0; sm.prod[1][t] = w1 * n0;
        sm.prod[2][t] = w0 * n1; sm.prod[3][t] = w1 * n1;
      }
      __syncthreads();

      // 6-conv pass: kin@new0, kin@new1, Vc@prod0..3
      float b0 = 0.f, b1 = 0.f, b2 = 0.f, b3 = 0.f, b4 = 0.f, b5 = 0.f;
      {
        const int jg = g * JPER;
#pragma unroll
        for (int b = 0; b < NBLK; ++b) {
          const int j0 = jg + 4 * b;
          const float4 x0 = *(const float4*)(nw0 + j0);
          const float4 x1 = *(const float4*)(nw1 + j0);
          const float4 q0 = *(const float4*)(sm.prod[0] + j0);
          const float4 q1 = *(const float4*)(sm.prod[1] + j0);
          const float4 q2 = *(const float4*)(sm.prod[2] + j0);
          const float4 q3 = *(const float4*)(sm.prod[3] + j0);
          const int base = i + 239 - j0;
          float ck, cv;
          ck = sm.cK[base    ]; cv = sm.cV[base    ];
          b0 += ck * x0.x; b1 += ck * x1.x; b2 += cv * q0.x; b3 += cv * q1.x; b4 += cv * q2.x; b5 += cv * q3.x;
          ck = sm.cK[base - 1]; cv = sm.cV[base - 1];
          b0 += ck * x0.y; b1 += ck * x1.y; b2 += cv * q0.y; b3 += cv * q1.y; b4 += cv * q2.y; b5 += cv * q3.y;
          ck = sm.cK[base - 2]; cv = sm.cV[base - 2];
          b0 += ck * x0.z; b1 += ck * x1.z; b2 += cv * q0.z; b3 += cv * q1.z; b4 += cv * q2.z; b5 += cv * q3.z;
          ck = sm.cK[base - 3]; cv = sm.cV[base - 3];
          b0 += ck * x0.w; b1 += ck * x1.w; b2 += cv * q0.w; b3 += cv * q1.w; b4 += cv * q2.w; b5 += cv * q3.w;
        }
      }
      sm.part[g][0][i] = b0; sm.part[g][1][i] = b1; sm.part[g][2][i] = b2;
      sm.part[g][3][i] = b3; sm.part[g][4][i] = b4; sm.part[g][5][i] = b5;
      __syncthreads();

      float re = 0.f, rp = 0.f;
      if (t < NXX) {
        float kn0 = sm.part[0][0][t] + sm.part[1][0][t];
        float kn1 = sm.part[0][1][t] + sm.part[1][1][t];
        float u00 = sm.part[0][2][t] + sm.part[1][2][t];
        float u01 = sm.part[0][3][t] + sm.part[1][3][t];
        float u10 = sm.part[0][4][t] + sm.part[1][4][t];
        float u11 = sm.part[0][5][t] + sm.part[1][5][t];
        float w0 = wf0[t], w1 = wf1[t];
        float n0 = nw0[t], n1 = nw1[t];
        float um0 = -delx * (w0 * u00 + w1 * u01) + Ut * n0;  // (Umf@new0)[t]
        float um1 = -delx * (w0 * u10 + w1 * u11) + Ut * n1;  // (Umf@new1)[t]
        re = n0 * kn0 + n1 * kn1;   // ekin integrand
        rp = n0 * um0 + n1 * um1;   // epot integrand
      }
      re = waveSum(re); rp = waveSum(rp);
      if (lane == 0) { sm.red5[0][wv] = re; sm.red5[1][wv] = rp; }
      __syncthreads();

      if (t == 0) {
        float ek   = sum8(sm.red5[0]) * delx;
        float ep   = sum8(sm.red5[1]) * delx;
        float s0   = sum8(sm.red1[2]) * delx;
        float s1   = sum8(sm.red1[3]) * delx;
        float eh   = sum8(sm.red1[4]) * delx * 0.5f;
        float esum = s0 + s1;
        float enerhfp = 0.5f * (esum + ek) + eh;
        float epot0hf = ep - 2.f * eh;
        float enerhf  = esum - 0.5f * epot0hf;
        out[0] = enerhf; out[1] = enerhfp; out[2] = ek;
        out[3] = eh;     out[4] = epot0hf; out[5] = esum;
      }
    }
    cur ^= 1;
  }
}

extern "C" void kernel_launch(void* const* d_in, const int* in_sizes, int n_in,
                              void* d_out, int out_size, void* d_ws, size_t ws_size,
                              hipStream_t stream) {
  const float* wfy0 = (const float*)d_in[0];
  const float* kin  = (const float*)d_in[1];
  const float* vnt  = (const float*)d_in[2];
  const float* uho  = (const float*)d_in[3];
  const float* delx = (const float*)d_in[4];
  const float* pfac = (const float*)d_in[5];
  const int*   itm  = (const int*)d_in[6];
  hipLaunchKernelGGL(hf_kernel, dim3(1), dim3(NTH), 0, stream,
                     wfy0, kin, vnt, uho, delx, pfac, itm, (float*)d_out);
}

// Round 3
// 2322.815 us; speedup vs baseline: 1.3700x; 1.3700x over previous
//
#include <hip/hip_runtime.h>

// Hartree-Fock SCF, NX=240, A_ORB=2, 500 sequential iterations.
// Single persistent workgroup (512 thr = 8 waves, 1 CU), state in LDS.
// kin/Vint are Toeplitz -> matvecs are length-240 convolutions.
// R1 restructure: per-thread register-resident Toeplitz windows (loaded once,
// reused 500 iters), R=4 outputs/lane, j split 8 ways over waves, broadcast-only
// LDS reads in the conv loop, and a single serial wave-0 vector phase with
// intra-wave shfl_xor reductions. 2 barriers/iter (was 6).
// R2 fix: mask pad rows (i >= 240) in the wave-0 vector phase — zero wb0/wb1
// on lanes l >= 60 so reductions exclude pads and all pad writes are 0.0,
// keeping the invariant that pads of wf/p arrays stay zero forever.

#define NXX  240
#define NPAD 256
#define NTH  512
#define JS   8     // j-split groups (= waves)
#define JCH  32    // j per wave
#define NQ   9     // register quads per coefficient window

__device__ __forceinline__ void allSum1(float& a) {
#pragma unroll
  for (int o = 1; o < 64; o <<= 1) a += __shfl_xor(a, o, 64);
}
__device__ __forceinline__ void allSum2(float& a, float& b) {
#pragma unroll
  for (int o = 1; o < 64; o <<= 1) {
    a += __shfl_xor(a, o, 64);
    b += __shfl_xor(b, o, 64);
  }
}
__device__ __forceinline__ void allSum3(float& a, float& b, float& c) {
#pragma unroll
  for (int o = 1; o < 64; o <<= 1) {
    a += __shfl_xor(a, o, 64);
    b += __shfl_xor(b, o, 64);
    c += __shfl_xor(c, o, 64);
  }
}

struct __align__(16) Smem {
  float cK[512];            // Toeplitz coeffs of kin, index d+256 (zero-padded)
  float cV[512];            // Toeplitz coeffs of Vint
  float uho[NPAD];
  float wfb[2][2][NPAD];    // ping-pong wavefunctions
  float p00[NPAD];
  float p01[NPAD];
  float p11[NPAD];
  float part[JS][6][NPAD];  // conv partials per j-group
};

__global__ void __launch_bounds__(NTH, 2)
hf_kernel(const float* __restrict__ wfy0,
          const float* __restrict__ kin,
          const float* __restrict__ vnt,
          const float* __restrict__ uho_g,
          const float* __restrict__ delx_p,
          const float* __restrict__ pfac_p,
          const int*   __restrict__ iter_p,
          float* __restrict__ out)
{
  __shared__ Smem sm;
  const int t  = (int)threadIdx.x;
  const int wv = t >> 6;
  const int l  = t & 63;
  const int i0 = 4 * l;          // output quad owned by this lane
  const int jg = wv * JCH;       // this wave's j-chunk
  const float delx = delx_p[0];
  const float pfac = pfac_p[0];
  const int itermax = iter_p[0];

  // ---- setup: Toeplitz coeffs (symmetric; col 0 / row 0), vectors ----
  for (int a = t; a < 512; a += NTH) {
    int d = a - 256;             // d = i - j
    float vk = 0.f, vv = 0.f;
    if (d >= 0 && d < NXX)      { vk = kin[(size_t)d * NXX]; vv = vnt[(size_t)d * NXX]; }
    else if (d < 0 && -d < NXX) { vk = kin[-d];              vv = vnt[-d]; }
    sm.cK[a] = vk; sm.cV[a] = vv;
  }
  if (t < NPAD) {
    float u  = (t < NXX) ? uho_g[t]        : 0.f;
    float a0 = (t < NXX) ? wfy0[2 * t]     : 0.f;
    float a1 = (t < NXX) ? wfy0[2 * t + 1] : 0.f;
    sm.uho[t] = u;
    sm.wfb[0][0][t] = a0; sm.wfb[0][1][t] = a1;
    sm.wfb[1][0][t] = 0.f; sm.wfb[1][1][t] = 0.f;
    sm.p00[t] = a0 * a0; sm.p01[t] = a0 * a1; sm.p11[t] = a1 * a1;
  }
  __syncthreads();

  // ---- persistent register coefficient windows (held 500 iterations) ----
  // block b uses quads [8-b] (hi) and [7-b] (lo); a = i - j + 256
  const int qbase = l - 8 * wv + 56;
  float4 rK[NQ], rV[NQ];
#pragma unroll
  for (int q = 0; q < NQ; ++q) {
    rK[q] = *(const float4*)&sm.cK[4 * (qbase + q)];
    rV[q] = *(const float4*)&sm.cV[4 * (qbase + q)];
  }

  int cur = 0;
  for (int it = 0; it < itermax; ++it) {
    const bool last = (it == itermax - 1);
    const float* wf0 = sm.wfb[cur][0];
    const float* wf1 = sm.wfb[cur][1];
    float* nw0 = sm.wfb[cur ^ 1][0];
    float* nw1 = sm.wfb[cur ^ 1][1];

    // ===== conv phase (all 8 waves): kin@wf0, kin@wf1, V@p00, V@p01, V@p11
    float aK0[4] = {0,0,0,0}, aK1[4] = {0,0,0,0};
    float aV0[4] = {0,0,0,0}, aV1[4] = {0,0,0,0}, aV2[4] = {0,0,0,0};
#pragma unroll
    for (int b = 0; b < 8; ++b) {
      const int j0 = jg + 4 * b;                       // wave-uniform -> broadcast
      const float4 x0 = *(const float4*)&wf0[j0];
      const float4 x1 = *(const float4*)&wf1[j0];
      const float4 y0 = *(const float4*)&sm.p00[j0];
      const float4 y1 = *(const float4*)&sm.p01[j0];
      const float4 y2 = *(const float4*)&sm.p11[j0];
      const float4 kh = rK[8 - b], kl = rK[7 - b];
      const float4 vh = rV[8 - b], vl = rV[7 - b];
      const float ck[8] = {kl.x, kl.y, kl.z, kl.w, kh.x, kh.y, kh.z, kh.w};
      const float cv[8] = {vl.x, vl.y, vl.z, vl.w, vh.x, vh.y, vh.z, vh.w};
      const float xs0[4] = {x0.x, x0.y, x0.z, x0.w};
      const float xs1[4] = {x1.x, x1.y, x1.z, x1.w};
      const float ys0[4] = {y0.x, y0.y, y0.z, y0.w};
      const float ys1[4] = {y1.x, y1.y, y1.z, y1.w};
      const float ys2[4] = {y2.x, y2.y, y2.z, y2.w};
#pragma unroll
      for (int s = 0; s < 4; ++s) {
#pragma unroll
        for (int r = 0; r < 4; ++r) {
          const int c = 4 + r - s;                     // compile-time index
          aK0[r] = fmaf(xs0[s], ck[c], aK0[r]);
          aK1[r] = fmaf(xs1[s], ck[c], aK1[r]);
          aV0[r] = fmaf(ys0[s], cv[c], aV0[r]);
          aV1[r] = fmaf(ys1[s], cv[c], aV1[r]);
          aV2[r] = fmaf(ys2[s], cv[c], aV2[r]);
        }
      }
    }
    *(float4*)&sm.part[wv][0][i0] = make_float4(aK0[0], aK0[1], aK0[2], aK0[3]);
    *(float4*)&sm.part[wv][1][i0] = make_float4(aK1[0], aK1[1], aK1[2], aK1[3]);
    *(float4*)&sm.part[wv][2][i0] = make_float4(aV0[0], aV0[1], aV0[2], aV0[3]);
    *(float4*)&sm.part[wv][3][i0] = make_float4(aV1[0], aV1[1], aV1[2], aV1[3]);
    *(float4*)&sm.part[wv][4][i0] = make_float4(aV2[0], aV2[1], aV2[2], aV2[3]);
    __syncthreads();   // B1

    // ===== serial wave-0 vector phase (registers + shfl reductions) =====
    float w0[4], w1[4], Ut[4], wff0[4], wff1[4], new0[4], new1[4];
    float spe0 = 0.f, spe1 = 0.f, eho = 0.f;

    if (wv == 0) {
      const bool valid = (l < 60);   // rows i0..i0+3 < 240 (quad-aligned)
      float k0[4]  = {0,0,0,0}, k1[4]  = {0,0,0,0};
      float v00[4] = {0,0,0,0}, v01[4] = {0,0,0,0}, v11[4] = {0,0,0,0};
#pragma unroll
      for (int g = 0; g < JS; ++g) {
        const float4 A0 = *(const float4*)&sm.part[g][0][i0];
        const float4 A1 = *(const float4*)&sm.part[g][1][i0];
        const float4 A2 = *(const float4*)&sm.part[g][2][i0];
        const float4 A3 = *(const float4*)&sm.part[g][3][i0];
        const float4 A4 = *(const float4*)&sm.part[g][4][i0];
        k0[0]  += A0.x; k0[1]  += A0.y; k0[2]  += A0.z; k0[3]  += A0.w;
        k1[0]  += A1.x; k1[1]  += A1.y; k1[2]  += A1.z; k1[3]  += A1.w;
        v00[0] += A2.x; v00[1] += A2.y; v00[2] += A2.z; v00[3] += A2.w;
        v01[0] += A3.x; v01[1] += A3.y; v01[2] += A3.z; v01[3] += A3.w;
        v11[0] += A4.x; v11[1] += A4.y; v11[2] += A4.z; v11[3] += A4.w;
      }
      const float4 w0q = *(const float4*)&wf0[i0];
      const float4 w1q = *(const float4*)&wf1[i0];
      const float4 uq  = *(const float4*)&sm.uho[i0];
      w0[0] = w0q.x; w0[1] = w0q.y; w0[2] = w0q.z; w0[3] = w0q.w;
      w1[0] = w1q.x; w1[1] = w1q.y; w1[2] = w1q.z; w1[3] = w1q.w;
      const float uh[4] = {uq.x, uq.y, uq.z, uq.w};

      float wb0[4], wb1[4];
      float s0 = 0.f, s1 = 0.f;
#pragma unroll
      for (int r = 0; r < 4; ++r) {
        Ut[r]   = delx * (v00[r] + v11[r]) + uh[r];          // Udir + U_HO
        wff0[r] = k0[r] - delx * (w0[r] * v00[r] + w1[r] * v01[r]) + Ut[r] * w0[r];
        wff1[r] = k1[r] - delx * (w0[r] * v01[r] + w1[r] * v11[r]) + Ut[r] * w1[r];
        wb0[r]  = w0[r] - pfac * wff0[r];
        wb1[r]  = w1[r] - pfac * wff1[r];
        if (!valid) { wb0[r] = 0.f; wb1[r] = 0.f; }   // mask pad rows
        s0 += wb0[r] * wb0[r];
        s1 += wb1[r] * wb1[r];
      }
      allSum2(s0, s1);
      const float nrm0 = s0 * delx, nrm1 = s1 * delx;
      const float sn0 = sqrtf(nrm0), sn1 = sqrtf(nrm1);
      float wfA[4], wfBp[4], sA = 0.f;
#pragma unroll
      for (int r = 0; r < 4; ++r) {
        wfA[r]  = wb0[r] / sn0;
        wfBp[r] = wb1[r] / sn1;
        sA += wfA[r] * wfA[r];
      }
      allSum1(sA);
      const float n2A = sA * delx;
      float sd = 0.f;
#pragma unroll
      for (int r = 0; r < 4; ++r) {
        new0[r] = 0.4f * (wfA[r] / n2A) + 0.6f * w0[r];
        sd += new0[r] * wfBp[r];
      }
      allSum1(sd);
      const float dB = sd * delx;
      float wfB2[4], sB = 0.f;
#pragma unroll
      for (int r = 0; r < 4; ++r) {
        wfB2[r] = wfBp[r] - new0[r] * dB;
        sB += wfB2[r] * wfB2[r];
      }
      allSum1(sB);
      const float n2B = sB * delx;
#pragma unroll
      for (int r = 0; r < 4; ++r)
        new1[r] = 0.4f * (wfB2[r] / n2B) + 0.6f * w1[r];

      *(float4*)&nw0[i0] = make_float4(new0[0], new0[1], new0[2], new0[3]);
      *(float4*)&nw1[i0] = make_float4(new1[0], new1[1], new1[2], new1[3]);
      *(float4*)&sm.p00[i0] =
          make_float4(new0[0]*new0[0], new0[1]*new0[1], new0[2]*new0[2], new0[3]*new0[3]);
      *(float4*)&sm.p01[i0] =
          make_float4(new0[0]*new1[0], new0[1]*new1[1], new0[2]*new1[2], new0[3]*new1[3]);
      *(float4*)&sm.p11[i0] =
          make_float4(new1[0]*new1[0], new1[1]*new1[1], new1[2]*new1[2], new1[3]*new1[3]);

      if (last) {
        float sp0 = 0.f, sp1 = 0.f, se = 0.f;
#pragma unroll
        for (int r = 0; r < 4; ++r) {
          sp0 += w0[r] * wff0[r];                       // spe integrands (w0=0 on pads)
          sp1 += w1[r] * wff1[r];
          se  += (w0[r] * w0[r] + w1[r] * w1[r]) * uh[r];  // eho integrand
        }
        allSum3(sp0, sp1, se);
        spe0 = sp0 * delx; spe1 = sp1 * delx; eho = se * delx * 0.5f;
      }
    }
    __syncthreads();   // B2 — next conv may read nw*/p* safely

    // ===== final iteration: ekin/epot via 6-conv pass =====
    if (last) {
      float bA[6][4] = {};
#pragma unroll
      for (int b = 0; b < 8; ++b) {
        const int j0 = jg + 4 * b;
        const float4 o0q = *(const float4*)&wf0[j0];
        const float4 o1q = *(const float4*)&wf1[j0];
        const float4 n0q = *(const float4*)&nw0[j0];
        const float4 n1q = *(const float4*)&nw1[j0];
        const float4 kh = rK[8 - b], kl = rK[7 - b];
        const float4 vh = rV[8 - b], vl = rV[7 - b];
        const float ck[8] = {kl.x, kl.y, kl.z, kl.w, kh.x, kh.y, kh.z, kh.w};
        const float cv[8] = {vl.x, vl.y, vl.z, vl.w, vh.x, vh.y, vh.z, vh.w};
        const float xo0[4] = {o0q.x, o0q.y, o0q.z, o0q.w};
        const float xo1[4] = {o1q.x, o1q.y, o1q.z, o1q.w};
        const float xn0[4] = {n0q.x, n0q.y, n0q.z, n0q.w};
        const float xn1[4] = {n1q.x, n1q.y, n1q.z, n1q.w};
#pragma unroll
        for (int s = 0; s < 4; ++s) {
          const float pr00 = xo0[s] * xn0[s];   // wf0*new0
          const float pr10 = xo1[s] * xn0[s];   // wf1*new0
          const float pr01 = xo0[s] * xn1[s];   // wf0*new1
          const float pr11 = xo1[s] * xn1[s];   // wf1*new1
#pragma unroll
          for (int r = 0; r < 4; ++r) {
            const int c = 4 + r - s;
            bA[0][r] = fmaf(xn0[s], ck[c], bA[0][r]);   // kin@new0
            bA[1][r] = fmaf(xn1[s], ck[c], bA[1][r]);   // kin@new1
            bA[2][r] = fmaf(pr00,  cv[c], bA[2][r]);    // V@(wf0*new0)
            bA[3][r] = fmaf(pr10,  cv[c], bA[3][r]);    // V@(wf1*new0)
            bA[4][r] = fmaf(pr01,  cv[c], bA[4][r]);    // V@(wf0*new1)
            bA[5][r] = fmaf(pr11,  cv[c], bA[5][r]);    // V@(wf1*new1)
          }
        }
      }
#pragma unroll
      for (int c = 0; c < 6; ++c)
        *(float4*)&sm.part[wv][c][i0] = make_float4(bA[c][0], bA[c][1], bA[c][2], bA[c][3]);
      __syncthreads();

      if (wv == 0) {
        float rd[6][4] = {};
#pragma unroll
        for (int g = 0; g < JS; ++g) {
#pragma unroll
          for (int c = 0; c < 6; ++c) {
            const float4 A = *(const float4*)&sm.part[g][c][i0];
            rd[c][0] += A.x; rd[c][1] += A.y; rd[c][2] += A.z; rd[c][3] += A.w;
          }
        }
        float re = 0.f, rp = 0.f;
#pragma unroll
        for (int r = 0; r < 4; ++r) {
          // pads contribute 0: w0=w1=new0=new1=0 there
          const float um0 = -delx * (w0[r] * rd[2][r] + w1[r] * rd[3][r]) + Ut[r] * new0[r];
          const float um1 = -delx * (w0[r] * rd[4][r] + w1[r] * rd[5][r]) + Ut[r] * new1[r];
          re += new0[r] * rd[0][r] + new1[r] * rd[1][r];
          rp += new0[r] * um0 + new1[r] * um1;
        }
        allSum2(re, rp);
        const float ekin = re * delx, epot = rp * delx;
        if (l == 0) {
          const float esum    = spe0 + spe1;
          const float enerhfp = 0.5f * (esum + ekin) + eho;
          const float epot0hf = epot - 2.f * eho;
          const float enerhf  = esum - 0.5f * epot0hf;
          out[0] = enerhf; out[1] = enerhfp; out[2] = ekin;
          out[3] = eho;    out[4] = epot0hf; out[5] = esum;
        }
      }
    }
    cur ^= 1;
  }
}

extern "C" void kernel_launch(void* const* d_in, const int* in_sizes, int n_in,
                              void* d_out, int out_size, void* d_ws, size_t ws_size,
                              hipStream_t stream) {
  const float* wfy0 = (const float*)d_in[0];
  const float* kin  = (const float*)d_in[1];
  const float* vnt  = (const float*)d_in[2];
  const float* uho  = (const float*)d_in[3];
  const float* delx = (const float*)d_in[4];
  const float* pfac = (const float*)d_in[5];
  const int*   itm  = (const int*)d_in[6];
  hipLaunchKernelGGL(hf_kernel, dim3(1), dim3(NTH), 0, stream,
                     wfy0, kin, vnt, uho, delx, pfac, itm, (float*)d_out);
}

// Round 4
// 1321.492 us; speedup vs baseline: 2.4080x; 1.7577x over previous
//
#include <hip/hip_runtime.h>

// Hartree-Fock SCF, NX=240, A_ORB=2, 500 sequential iterations.
// Single persistent workgroup (512 thr = 8 waves, 1 CU), state in LDS.
// Toeplitz kin/Vint -> matvecs are length-240 convolutions with per-thread
// register-resident coefficient windows (16 quads, loaded once).
// R3: (a) wave-0 reductions via DPP butterflies (VALU pipe, ~60cy) instead of
// __shfl_xor (DS pipe, ~600cy); (b) conv re-split: waves 0-3 do kin convs
// (cK window), waves 4-7 do Vint convs (cV window), j-quarters of exactly 240
// -> 4 partials/array (combine = 20 b128 reads, was 40) and no j-pad waste;
// (c) divisions -> reciprocal multiplies in the serial chain.

#define NXX  240
#define NPAD 256
#define NTH  512
#define JCH  60    // j per group (4 groups cover 240 exactly)
#define NBLK 15    // JCH/4
#define NQW  16    // register quads per coefficient window

// ---- wave64 all-reduce via DPP: 6 dependent v_add+dpp, result in lane 63 ----
template <int CTRL>
__device__ __forceinline__ float dppAddStep(float x) {
  int s = __builtin_amdgcn_update_dpp(0, __float_as_int(x), CTRL, 0xF, 0xF, false);
  return x + __int_as_float(s);
}
__device__ __forceinline__ float waveSumDpp(float x) {
  x = dppAddStep<0xB1>(x);   // quad_perm [1,0,3,2] : xor 1
  x = dppAddStep<0x4E>(x);   // quad_perm [2,3,0,1] : xor 2
  x = dppAddStep<0x141>(x);  // row_half_mirror     : xor 7
  x = dppAddStep<0x140>(x);  // row_mirror          : xor 15
  x = dppAddStep<0x142>(x);  // row_bcast:15  (rows 1,3 += rows 0,2)
  x = dppAddStep<0x143>(x);  // row_bcast:31  (rows 2,3 += rows 0,1)
  return __int_as_float(__builtin_amdgcn_readlane(__float_as_int(x), 63));
}

struct __align__(16) Smem {
  float cK[512];            // Toeplitz coeffs of kin, index d+256 (zero-padded)
  float cV[512];            // Toeplitz coeffs of Vint
  float uho[NPAD];
  float wfb[2][2][NPAD];    // ping-pong wavefunctions
  float p00[NPAD];
  float p01[NPAD];
  float p11[NPAD];
  float part[4][6][NPAD];   // conv partials per j-group
};

__global__ void __launch_bounds__(NTH, 2)
hf_kernel(const float* __restrict__ wfy0,
          const float* __restrict__ kin,
          const float* __restrict__ vnt,
          const float* __restrict__ uho_g,
          const float* __restrict__ delx_p,
          const float* __restrict__ pfac_p,
          const int*   __restrict__ iter_p,
          float* __restrict__ out)
{
  __shared__ Smem sm;
  const int t  = (int)threadIdx.x;
  const int wv = t >> 6;
  const int l  = t & 63;
  const int i0 = 4 * l;              // output quad owned by this lane
  const bool isK = (wv < 4);
  const int g  = isK ? wv : wv - 4;  // j-group 0..3
  const int jg = g * JCH;
  const float delx = delx_p[0];
  const float pfac = pfac_p[0];
  const int itermax = iter_p[0];

  // ---- setup: Toeplitz coeffs (symmetric; col 0 / row 0), vectors ----
  for (int a = t; a < 512; a += NTH) {
    int d = a - 256;                 // d = i - j
    float vk = 0.f, vv = 0.f;
    if (d >= 0 && d < NXX)      { vk = kin[(size_t)d * NXX]; vv = vnt[(size_t)d * NXX]; }
    else if (d < 0 && -d < NXX) { vk = kin[-d];              vv = vnt[-d]; }
    sm.cK[a] = vk; sm.cV[a] = vv;
  }
  if (t < NPAD) {
    float u  = (t < NXX) ? uho_g[t]        : 0.f;
    float a0 = (t < NXX) ? wfy0[2 * t]     : 0.f;
    float a1 = (t < NXX) ? wfy0[2 * t + 1] : 0.f;
    sm.uho[t] = u;
    sm.wfb[0][0][t] = a0; sm.wfb[0][1][t] = a1;
    sm.wfb[1][0][t] = 0.f; sm.wfb[1][1][t] = 0.f;
    sm.p00[t] = a0 * a0; sm.p01[t] = a0 * a1; sm.p11[t] = a1 * a1;
  }
  __syncthreads();

  // ---- persistent register coefficient window (held all iterations) ----
  // quad m covers a = 4*(qb+m)..+3, a = (i-j)+256; block b uses m = 14-b,15-b
  const int qb = l - 15 * g + 49;
  const float* tab = isK ? sm.cK : sm.cV;
  float4 cw[NQW];
#pragma unroll
  for (int m = 0; m < NQW; ++m)
    cw[m] = *(const float4*)&tab[4 * (qb + m)];

  int cur = 0;
  for (int it = 0; it < itermax; ++it) {
    const bool last = (it == itermax - 1);
    const float* wf0 = sm.wfb[cur][0];
    const float* wf1 = sm.wfb[cur][1];
    float* nw0 = sm.wfb[cur ^ 1][0];
    float* nw1 = sm.wfb[cur ^ 1][1];

    // ===== conv phase: K-waves: kin@wf0, kin@wf1 ; V-waves: V@p00,p01,p11 =====
    if (isK) {
      float aK0[4] = {0,0,0,0}, aK1[4] = {0,0,0,0};
#pragma unroll
      for (int b = 0; b < NBLK; ++b) {
        const int j0 = jg + 4 * b;                     // wave-uniform -> broadcast
        const float4 x0 = *(const float4*)&wf0[j0];
        const float4 x1 = *(const float4*)&wf1[j0];
        const float4 kh = cw[15 - b], kl = cw[14 - b];
        const float ck[8] = {kl.x, kl.y, kl.z, kl.w, kh.x, kh.y, kh.z, kh.w};
        const float xs0[4] = {x0.x, x0.y, x0.z, x0.w};
        const float xs1[4] = {x1.x, x1.y, x1.z, x1.w};
#pragma unroll
        for (int s = 0; s < 4; ++s) {
#pragma unroll
          for (int r = 0; r < 4; ++r) {
            const int c = 4 + r - s;
            aK0[r] = fmaf(xs0[s], ck[c], aK0[r]);
            aK1[r] = fmaf(xs1[s], ck[c], aK1[r]);
          }
        }
      }
      *(float4*)&sm.part[g][0][i0] = make_float4(aK0[0], aK0[1], aK0[2], aK0[3]);
      *(float4*)&sm.part[g][1][i0] = make_float4(aK1[0], aK1[1], aK1[2], aK1[3]);
    } else {
      float aV0[4] = {0,0,0,0}, aV1[4] = {0,0,0,0}, aV2[4] = {0,0,0,0};
#pragma unroll
      for (int b = 0; b < NBLK; ++b) {
        const int j0 = jg + 4 * b;
        const float4 y0 = *(const float4*)&sm.p00[j0];
        const float4 y1 = *(const float4*)&sm.p01[j0];
        const float4 y2 = *(const float4*)&sm.p11[j0];
        const float4 vh = cw[15 - b], vl = cw[14 - b];
        const float cv[8] = {vl.x, vl.y, vl.z, vl.w, vh.x, vh.y, vh.z, vh.w};
        const float ys0[4] = {y0.x, y0.y, y0.z, y0.w};
        const float ys1[4] = {y1.x, y1.y, y1.z, y1.w};
        const float ys2[4] = {y2.x, y2.y, y2.z, y2.w};
#pragma unroll
        for (int s = 0; s < 4; ++s) {
#pragma unroll
          for (int r = 0; r < 4; ++r) {
            const int c = 4 + r - s;
            aV0[r] = fmaf(ys0[s], cv[c], aV0[r]);
            aV1[r] = fmaf(ys1[s], cv[c], aV1[r]);
            aV2[r] = fmaf(ys2[s], cv[c], aV2[r]);
          }
        }
      }
      *(float4*)&sm.part[g][2][i0] = make_float4(aV0[0], aV0[1], aV0[2], aV0[3]);
      *(float4*)&sm.part[g][3][i0] = make_float4(aV1[0], aV1[1], aV1[2], aV1[3]);
      *(float4*)&sm.part[g][4][i0] = make_float4(aV2[0], aV2[1], aV2[2], aV2[3]);
    }
    __syncthreads();   // B1

    // ===== serial wave-0 vector phase (registers + DPP reductions) =====
    float w0[4], w1[4], Ut[4], wff0[4], wff1[4], new0[4], new1[4];
    float spe0 = 0.f, spe1 = 0.f, eho = 0.f;

    if (wv == 0) {
      const bool valid = (l < 60);   // rows i0..i0+3 < 240
      float k0[4]  = {0,0,0,0}, k1[4]  = {0,0,0,0};
      float v00[4] = {0,0,0,0}, v01[4] = {0,0,0,0}, v11[4] = {0,0,0,0};
#pragma unroll
      for (int gg = 0; gg < 4; ++gg) {
        const float4 A0 = *(const float4*)&sm.part[gg][0][i0];
        const float4 A1 = *(const float4*)&sm.part[gg][1][i0];
        const float4 A2 = *(const float4*)&sm.part[gg][2][i0];
        const float4 A3 = *(const float4*)&sm.part[gg][3][i0];
        const float4 A4 = *(const float4*)&sm.part[gg][4][i0];
        k0[0]  += A0.x; k0[1]  += A0.y; k0[2]  += A0.z; k0[3]  += A0.w;
        k1[0]  += A1.x; k1[1]  += A1.y; k1[2]  += A1.z; k1[3]  += A1.w;
        v00[0] += A2.x; v00[1] += A2.y; v00[2] += A2.z; v00[3] += A2.w;
        v01[0] += A3.x; v01[1] += A3.y; v01[2] += A3.z; v01[3] += A3.w;
        v11[0] += A4.x; v11[1] += A4.y; v11[2] += A4.z; v11[3] += A4.w;
      }
      const float4 w0q = *(const float4*)&wf0[i0];
      const float4 w1q = *(const float4*)&wf1[i0];
      const float4 uq  = *(const float4*)&sm.uho[i0];
      w0[0] = w0q.x; w0[1] = w0q.y; w0[2] = w0q.z; w0[3] = w0q.w;
      w1[0] = w1q.x; w1[1] = w1q.y; w1[2] = w1q.z; w1[3] = w1q.w;
      const float uh[4] = {uq.x, uq.y, uq.z, uq.w};

      float wb0[4], wb1[4];
      float s0 = 0.f, s1 = 0.f;
#pragma unroll
      for (int r = 0; r < 4; ++r) {
        Ut[r]   = delx * (v00[r] + v11[r]) + uh[r];          // Udir + U_HO
        wff0[r] = k0[r] - delx * (w0[r] * v00[r] + w1[r] * v01[r]) + Ut[r] * w0[r];
        wff1[r] = k1[r] - delx * (w0[r] * v01[r] + w1[r] * v11[r]) + Ut[r] * w1[r];
        wb0[r]  = w0[r] - pfac * wff0[r];
        wb1[r]  = w1[r] - pfac * wff1[r];
        if (!valid) { wb0[r] = 0.f; wb1[r] = 0.f; }          // mask pad rows
        s0 += wb0[r] * wb0[r];
        s1 += wb1[r] * wb1[r];
      }
      s0 = waveSumDpp(s0);
      s1 = waveSumDpp(s1);
      const float inv0 = 1.f / sqrtf(s0 * delx);
      const float inv1 = 1.f / sqrtf(s1 * delx);
      float wfA[4], wfBp[4], sA = 0.f;
#pragma unroll
      for (int r = 0; r < 4; ++r) {
        wfA[r]  = wb0[r] * inv0;
        wfBp[r] = wb1[r] * inv1;
        sA += wfA[r] * wfA[r];
      }
      sA = waveSumDpp(sA);
      const float invA = 1.f / (sA * delx);
      float sd = 0.f;
#pragma unroll
      for (int r = 0; r < 4; ++r) {
        new0[r] = 0.4f * (wfA[r] * invA) + 0.6f * w0[r];
        sd += new0[r] * wfBp[r];
      }
      sd = waveSumDpp(sd);
      const float dB = sd * delx;
      float wfB2[4], sB = 0.f;
#pragma unroll
      for (int r = 0; r < 4; ++r) {
        wfB2[r] = wfBp[r] - new0[r] * dB;
        sB += wfB2[r] * wfB2[r];
      }
      sB = waveSumDpp(sB);
      const float invB = 1.f / (sB * delx);
#pragma unroll
      for (int r = 0; r < 4; ++r)
        new1[r] = 0.4f * (wfB2[r] * invB) + 0.6f * w1[r];

      *(float4*)&nw0[i0] = make_float4(new0[0], new0[1], new0[2], new0[3]);
      *(float4*)&nw1[i0] = make_float4(new1[0], new1[1], new1[2], new1[3]);
      *(float4*)&sm.p00[i0] =
          make_float4(new0[0]*new0[0], new0[1]*new0[1], new0[2]*new0[2], new0[3]*new0[3]);
      *(float4*)&sm.p01[i0] =
          make_float4(new0[0]*new1[0], new0[1]*new1[1], new0[2]*new1[2], new0[3]*new1[3]);
      *(float4*)&sm.p11[i0] =
          make_float4(new1[0]*new1[0], new1[1]*new1[1], new1[2]*new1[2], new1[3]*new1[3]);

      if (last) {
        float sp0 = 0.f, sp1 = 0.f, se = 0.f;
#pragma unroll
        for (int r = 0; r < 4; ++r) {
          sp0 += w0[r] * wff0[r];                            // w0=0 on pads
          sp1 += w1[r] * wff1[r];
          se  += (w0[r] * w0[r] + w1[r] * w1[r]) * uh[r];
        }
        sp0 = waveSumDpp(sp0);
        sp1 = waveSumDpp(sp1);
        se  = waveSumDpp(se);
        spe0 = sp0 * delx; spe1 = sp1 * delx; eho = se * delx * 0.5f;
      }
    }
    __syncthreads();   // B2 — next conv may read nw*/p* safely

    // ===== final iteration: ekin/epot via 6-conv pass =====
    if (last) {
      if (isK) {
        float bA0[4] = {0,0,0,0}, bA1[4] = {0,0,0,0};
#pragma unroll
        for (int b = 0; b < NBLK; ++b) {
          const int j0 = jg + 4 * b;
          const float4 n0q = *(const float4*)&nw0[j0];
          const float4 n1q = *(const float4*)&nw1[j0];
          const float4 kh = cw[15 - b], kl = cw[14 - b];
          const float ck[8] = {kl.x, kl.y, kl.z, kl.w, kh.x, kh.y, kh.z, kh.w};
          const float xn0[4] = {n0q.x, n0q.y, n0q.z, n0q.w};
          const float xn1[4] = {n1q.x, n1q.y, n1q.z, n1q.w};
#pragma unroll
          for (int s = 0; s < 4; ++s) {
#pragma unroll
            for (int r = 0; r < 4; ++r) {
              const int c = 4 + r - s;
              bA0[r] = fmaf(xn0[s], ck[c], bA0[r]);          // kin@new0
              bA1[r] = fmaf(xn1[s], ck[c], bA1[r]);          // kin@new1
            }
          }
        }
        *(float4*)&sm.part[g][0][i0] = make_float4(bA0[0], bA0[1], bA0[2], bA0[3]);
        *(float4*)&sm.part[g][1][i0] = make_float4(bA1[0], bA1[1], bA1[2], bA1[3]);
      } else {
        float bV[4][4] = {};
#pragma unroll
        for (int b = 0; b < NBLK; ++b) {
          const int j0 = jg + 4 * b;
          const float4 o0q = *(const float4*)&wf0[j0];
          const float4 o1q = *(const float4*)&wf1[j0];
          const float4 n0q = *(const float4*)&nw0[j0];
          const float4 n1q = *(const float4*)&nw1[j0];
          const float4 vh = cw[15 - b], vl = cw[14 - b];
          const float cv[8] = {vl.x, vl.y, vl.z, vl.w, vh.x, vh.y, vh.z, vh.w};
          const float xo0[4] = {o0q.x, o0q.y, o0q.z, o0q.w};
          const float xo1[4] = {o1q.x, o1q.y, o1q.z, o1q.w};
          const float xn0[4] = {n0q.x, n0q.y, n0q.z, n0q.w};
          const float xn1[4] = {n1q.x, n1q.y, n1q.z, n1q.w};
#pragma unroll
          for (int s = 0; s < 4; ++s) {
            const float pr00 = xo0[s] * xn0[s];
            const float pr10 = xo1[s] * xn0[s];
            const float pr01 = xo0[s] * xn1[s];
            const float pr11 = xo1[s] * xn1[s];
#pragma unroll
            for (int r = 0; r < 4; ++r) {
              const int c = 4 + r - s;
              bV[0][r] = fmaf(pr00, cv[c], bV[0][r]);        // V@(wf0*new0)
              bV[1][r] = fmaf(pr10, cv[c], bV[1][r]);        // V@(wf1*new0)
              bV[2][r] = fmaf(pr01, cv[c], bV[2][r]);        // V@(wf0*new1)
              bV[3][r] = fmaf(pr11, cv[c], bV[3][r]);        // V@(wf1*new1)
            }
          }
        }
#pragma unroll
        for (int c2 = 0; c2 < 4; ++c2)
          *(float4*)&sm.part[g][2 + c2][i0] =
              make_float4(bV[c2][0], bV[c2][1], bV[c2][2], bV[c2][3]);
      }
      __syncthreads();

      if (wv == 0) {
        float rd[6][4] = {};
#pragma unroll
        for (int gg = 0; gg < 4; ++gg) {
#pragma unroll
          for (int c = 0; c < 6; ++c) {
            const float4 A = *(const float4*)&sm.part[gg][c][i0];
            rd[c][0] += A.x; rd[c][1] += A.y; rd[c][2] += A.z; rd[c][3] += A.w;
          }
        }
        float re = 0.f, rp = 0.f;
#pragma unroll
        for (int r = 0; r < 4; ++r) {
          // pads contribute 0: w0=w1=new0=new1=0 there
          const float um0 = -delx * (w0[r] * rd[2][r] + w1[r] * rd[3][r]) + Ut[r] * new0[r];
          const float um1 = -delx * (w0[r] * rd[4][r] + w1[r] * rd[5][r]) + Ut[r] * new1[r];
          re += new0[r] * rd[0][r] + new1[r] * rd[1][r];
          rp += new0[r] * um0 + new1[r] * um1;
        }
        re = waveSumDpp(re);
        rp = waveSumDpp(rp);
        const float ekin = re * delx, epot = rp * delx;
        if (l == 0) {
          const float esum    = spe0 + spe1;
          const float enerhfp = 0.5f * (esum + ekin) + eho;
          const float epot0hf = epot - 2.f * eho;
          const float enerhf  = esum - 0.5f * epot0hf;
          out[0] = enerhf; out[1] = enerhfp; out[2] = ekin;
          out[3] = eho;    out[4] = epot0hf; out[5] = esum;
        }
      }
    }
    cur ^= 1;
  }
}

extern "C" void kernel_launch(void* const* d_in, const int* in_sizes, int n_in,
                              void* d_out, int out_size, void* d_ws, size_t ws_size,
                              hipStream_t stream) {
  const float* wfy0 = (const float*)d_in[0];
  const float* kin  = (const float*)d_in[1];
  const float* vnt  = (const float*)d_in[2];
  const float* uho  = (const float*)d_in[3];
  const float* delx = (const float*)d_in[4];
  const float* pfac = (const float*)d_in[5];
  const int*   itm  = (const int*)d_in[6];
  hipLaunchKernelGGL(hf_kernel, dim3(1), dim3(NTH), 0, stream,
                     wfy0, kin, vnt, uho, delx, pfac, itm, (float*)d_out);
}

// Round 5
// 1282.055 us; speedup vs baseline: 2.4821x; 1.0308x over previous
//
#include <hip/hip_runtime.h>

// Hartree-Fock SCF, NX=240, A_ORB=2, 500 sequential iterations.
// Single persistent workgroup (512 thr = 8 waves, 1 CU), state in LDS.
// Toeplitz kin/Vint -> matvecs are length-240 convolutions with per-thread
// register-resident coefficient windows (16 quads, loaded once).
// R3: DPP reductions; conv split K-waves/V-waves over j-quarters.
// R4: Gram-Schmidt collapsed to ONE batched 6-way DPP reduction using
//   n2A == 1 and ||wfBp||^2 == 1/delx identities plus algebraic expansion of
//   the projection/normalization in the {wb0, wb1, w0} basis. Serial chain:
//   combine -> 6-sum reduce -> ~15 scalar ops -> vector update. (was 4
//   sequential reduce stages).

#define NXX  240
#define NPAD 256
#define NTH  512
#define JCH  60    // j per group (4 groups cover 240 exactly)
#define NBLK 15    // JCH/4
#define NQW  16    // register quads per coefficient window

// ---- wave64 all-reduce via DPP, N interleaved chains; result broadcast ----
template <int CTRL, int N>
__device__ __forceinline__ void dppStepN(float (&v)[N]) {
#pragma unroll
  for (int k = 0; k < N; ++k) {
    int s = __builtin_amdgcn_update_dpp(0, __float_as_int(v[k]), CTRL, 0xF, 0xF, false);
    v[k] += __int_as_float(s);
  }
}
template <int N>
__device__ __forceinline__ void waveSumDppN(float (&v)[N]) {
  dppStepN<0xB1>(v);   // quad_perm xor1
  dppStepN<0x4E>(v);   // quad_perm xor2
  dppStepN<0x141>(v);  // row_half_mirror (xor 7)
  dppStepN<0x140>(v);  // row_mirror (xor 15)
  dppStepN<0x142>(v);  // row_bcast:15
  dppStepN<0x143>(v);  // row_bcast:31
#pragma unroll
  for (int k = 0; k < N; ++k)
    v[k] = __int_as_float(__builtin_amdgcn_readlane(__float_as_int(v[k]), 63));
}

struct __align__(16) Smem {
  float cK[512];            // Toeplitz coeffs of kin, index d+256 (zero-padded)
  float cV[512];            // Toeplitz coeffs of Vint
  float uho[NPAD];
  float wfb[2][2][NPAD];    // ping-pong wavefunctions
  float p00[NPAD];
  float p01[NPAD];
  float p11[NPAD];
  float part[4][6][NPAD];   // conv partials per j-group
};

__global__ void __launch_bounds__(NTH, 2)
hf_kernel(const float* __restrict__ wfy0,
          const float* __restrict__ kin,
          const float* __restrict__ vnt,
          const float* __restrict__ uho_g,
          const float* __restrict__ delx_p,
          const float* __restrict__ pfac_p,
          const int*   __restrict__ iter_p,
          float* __restrict__ out)
{
  __shared__ Smem sm;
  const int t  = (int)threadIdx.x;
  const int wv = t >> 6;
  const int l  = t & 63;
  const int i0 = 4 * l;              // output quad owned by this lane
  const bool isK = (wv < 4);
  const int g  = isK ? wv : wv - 4;  // j-group 0..3
  const int jg = g * JCH;
  const float delx = delx_p[0];
  const float pfac = pfac_p[0];
  const int itermax = iter_p[0];

  // ---- setup: Toeplitz coeffs (symmetric; col 0 / row 0), vectors ----
  for (int a = t; a < 512; a += NTH) {
    int d = a - 256;                 // d = i - j
    float vk = 0.f, vv = 0.f;
    if (d >= 0 && d < NXX)      { vk = kin[(size_t)d * NXX]; vv = vnt[(size_t)d * NXX]; }
    else if (d < 0 && -d < NXX) { vk = kin[-d];              vv = vnt[-d]; }
    sm.cK[a] = vk; sm.cV[a] = vv;
  }
  if (t < NPAD) {
    float u  = (t < NXX) ? uho_g[t]        : 0.f;
    float a0 = (t < NXX) ? wfy0[2 * t]     : 0.f;
    float a1 = (t < NXX) ? wfy0[2 * t + 1] : 0.f;
    sm.uho[t] = u;
    sm.wfb[0][0][t] = a0; sm.wfb[0][1][t] = a1;
    sm.wfb[1][0][t] = 0.f; sm.wfb[1][1][t] = 0.f;
    sm.p00[t] = a0 * a0; sm.p01[t] = a0 * a1; sm.p11[t] = a1 * a1;
  }
  __syncthreads();

  // ---- persistent register coefficient window (held all iterations) ----
  // quad m covers a = 4*(qb+m)..+3, a = (i-j)+256; block b uses m = 14-b,15-b
  const int qb = l - 15 * g + 49;
  const float* tab = isK ? sm.cK : sm.cV;
  float4 cw[NQW];
#pragma unroll
  for (int m = 0; m < NQW; ++m)
    cw[m] = *(const float4*)&tab[4 * (qb + m)];

  int cur = 0;
  for (int it = 0; it < itermax; ++it) {
    const bool last = (it == itermax - 1);
    const float* wf0 = sm.wfb[cur][0];
    const float* wf1 = sm.wfb[cur][1];
    float* nw0 = sm.wfb[cur ^ 1][0];
    float* nw1 = sm.wfb[cur ^ 1][1];

    // ===== conv phase: K-waves: kin@wf0, kin@wf1 ; V-waves: V@p00,p01,p11 =====
    if (isK) {
      float aK0[4] = {0,0,0,0}, aK1[4] = {0,0,0,0};
#pragma unroll
      for (int b = 0; b < NBLK; ++b) {
        const int j0 = jg + 4 * b;                     // wave-uniform -> broadcast
        const float4 x0 = *(const float4*)&wf0[j0];
        const float4 x1 = *(const float4*)&wf1[j0];
        const float4 kh = cw[15 - b], kl = cw[14 - b];
        const float ck[8] = {kl.x, kl.y, kl.z, kl.w, kh.x, kh.y, kh.z, kh.w};
        const float xs0[4] = {x0.x, x0.y, x0.z, x0.w};
        const float xs1[4] = {x1.x, x1.y, x1.z, x1.w};
#pragma unroll
        for (int s = 0; s < 4; ++s) {
#pragma unroll
          for (int r = 0; r < 4; ++r) {
            const int c = 4 + r - s;
            aK0[r] = fmaf(xs0[s], ck[c], aK0[r]);
            aK1[r] = fmaf(xs1[s], ck[c], aK1[r]);
          }
        }
      }
      *(float4*)&sm.part[g][0][i0] = make_float4(aK0[0], aK0[1], aK0[2], aK0[3]);
      *(float4*)&sm.part[g][1][i0] = make_float4(aK1[0], aK1[1], aK1[2], aK1[3]);
    } else {
      float aV0[4] = {0,0,0,0}, aV1[4] = {0,0,0,0}, aV2[4] = {0,0,0,0};
#pragma unroll
      for (int b = 0; b < NBLK; ++b) {
        const int j0 = jg + 4 * b;
        const float4 y0 = *(const float4*)&sm.p00[j0];
        const float4 y1 = *(const float4*)&sm.p01[j0];
        const float4 y2 = *(const float4*)&sm.p11[j0];
        const float4 vh = cw[15 - b], vl = cw[14 - b];
        const float cv[8] = {vl.x, vl.y, vl.z, vl.w, vh.x, vh.y, vh.z, vh.w};
        const float ys0[4] = {y0.x, y0.y, y0.z, y0.w};
        const float ys1[4] = {y1.x, y1.y, y1.z, y1.w};
        const float ys2[4] = {y2.x, y2.y, y2.z, y2.w};
#pragma unroll
        for (int s = 0; s < 4; ++s) {
#pragma unroll
          for (int r = 0; r < 4; ++r) {
            const int c = 4 + r - s;
            aV0[r] = fmaf(ys0[s], cv[c], aV0[r]);
            aV1[r] = fmaf(ys1[s], cv[c], aV1[r]);
            aV2[r] = fmaf(ys2[s], cv[c], aV2[r]);
          }
        }
      }
      *(float4*)&sm.part[g][2][i0] = make_float4(aV0[0], aV0[1], aV0[2], aV0[3]);
      *(float4*)&sm.part[g][3][i0] = make_float4(aV1[0], aV1[1], aV1[2], aV1[3]);
      *(float4*)&sm.part[g][4][i0] = make_float4(aV2[0], aV2[1], aV2[2], aV2[3]);
    }
    __syncthreads();   // B1

    // ===== serial wave-0 vector phase: ONE batched reduction =====
    float w0[4], w1[4], Ut[4], wff0[4], wff1[4], new0[4], new1[4];
    float spe0 = 0.f, spe1 = 0.f, eho = 0.f;

    if (wv == 0) {
      const bool valid = (l < 60);   // rows i0..i0+3 < 240
      float k0[4]  = {0,0,0,0}, k1[4]  = {0,0,0,0};
      float v00[4] = {0,0,0,0}, v01[4] = {0,0,0,0}, v11[4] = {0,0,0,0};
#pragma unroll
      for (int gg = 0; gg < 4; ++gg) {
        const float4 A0 = *(const float4*)&sm.part[gg][0][i0];
        const float4 A1 = *(const float4*)&sm.part[gg][1][i0];
        const float4 A2 = *(const float4*)&sm.part[gg][2][i0];
        const float4 A3 = *(const float4*)&sm.part[gg][3][i0];
        const float4 A4 = *(const float4*)&sm.part[gg][4][i0];
        k0[0]  += A0.x; k0[1]  += A0.y; k0[2]  += A0.z; k0[3]  += A0.w;
        k1[0]  += A1.x; k1[1]  += A1.y; k1[2]  += A1.z; k1[3]  += A1.w;
        v00[0] += A2.x; v00[1] += A2.y; v00[2] += A2.z; v00[3] += A2.w;
        v01[0] += A3.x; v01[1] += A3.y; v01[2] += A3.z; v01[3] += A3.w;
        v11[0] += A4.x; v11[1] += A4.y; v11[2] += A4.z; v11[3] += A4.w;
      }
      const float4 w0q = *(const float4*)&wf0[i0];
      const float4 w1q = *(const float4*)&wf1[i0];
      const float4 uq  = *(const float4*)&sm.uho[i0];
      w0[0] = w0q.x; w0[1] = w0q.y; w0[2] = w0q.z; w0[3] = w0q.w;
      w1[0] = w1q.x; w1[1] = w1q.y; w1[2] = w1q.z; w1[3] = w1q.w;
      const float uh[4] = {uq.x, uq.y, uq.z, uq.w};

      float wb0[4], wb1[4];
      float red[6] = {0, 0, 0, 0, 0, 0};  // s0, s1, c01, d01, a00, sw0
#pragma unroll
      for (int r = 0; r < 4; ++r) {
        Ut[r]   = delx * (v00[r] + v11[r]) + uh[r];          // Udir + U_HO
        wff0[r] = k0[r] - delx * (w0[r] * v00[r] + w1[r] * v01[r]) + Ut[r] * w0[r];
        wff1[r] = k1[r] - delx * (w0[r] * v01[r] + w1[r] * v11[r]) + Ut[r] * w1[r];
        wb0[r]  = w0[r] - pfac * wff0[r];
        wb1[r]  = w1[r] - pfac * wff1[r];
        if (!valid) { wb0[r] = 0.f; wb1[r] = 0.f; }          // mask pad rows
        red[0] += wb0[r] * wb0[r];
        red[1] += wb1[r] * wb1[r];
        red[2] += wb0[r] * wb1[r];
        red[3] += w0[r]  * wb1[r];
        red[4] += wb0[r] * w0[r];
        red[5] += w0[r]  * w0[r];
      }
      waveSumDppN<6>(red);
      const float rdelx = 1.f / delx;
      const float inv0 = 1.f / sqrtf(red[0] * delx);   // 1/||wb0||
      const float inv1 = 1.f / sqrtf(red[1] * delx);   // 1/||wb1||
      // dB = delx * sum(new0 * wfBp)
      const float dB = delx * inv1 * (0.4f * red[2] * inv0 + 0.6f * red[3]);
      // e0 = sum(new0^2) = 0.16/delx + 0.48*a00*inv0 + 0.36*sw0
      const float e0 = 0.16f * rdelx + 0.48f * red[4] * inv0 + 0.36f * red[5];
      // sB = sum(wfB2^2) = 1/delx - dB^2*(2/delx - e0)
      const float sB = rdelx - dB * dB * (2.f * rdelx - e0);
      const float invB = 1.f / (sB * delx);
#pragma unroll
      for (int r = 0; r < 4; ++r) {
        const float wfA  = wb0[r] * inv0;
        const float wfBp = wb1[r] * inv1;
        new0[r] = 0.4f * wfA + 0.6f * w0[r];           // n2A == 1 identity
        const float wfB2 = wfBp - new0[r] * dB;
        new1[r] = 0.4f * wfB2 * invB + 0.6f * w1[r];
      }
      *(float4*)&nw0[i0] = make_float4(new0[0], new0[1], new0[2], new0[3]);
      *(float4*)&nw1[i0] = make_float4(new1[0], new1[1], new1[2], new1[3]);
      *(float4*)&sm.p00[i0] =
          make_float4(new0[0]*new0[0], new0[1]*new0[1], new0[2]*new0[2], new0[3]*new0[3]);
      *(float4*)&sm.p01[i0] =
          make_float4(new0[0]*new1[0], new0[1]*new1[1], new0[2]*new1[2], new0[3]*new1[3]);
      *(float4*)&sm.p11[i0] =
          make_float4(new1[0]*new1[0], new1[1]*new1[1], new1[2]*new1[2], new1[3]*new1[3]);

      if (last) {
        float er[3] = {0, 0, 0};                       // spe0, spe1, eho
#pragma unroll
        for (int r = 0; r < 4; ++r) {
          er[0] += w0[r] * wff0[r];                    // w0=0 on pads
          er[1] += w1[r] * wff1[r];
          er[2] += (w0[r] * w0[r] + w1[r] * w1[r]) * uh[r];
        }
        waveSumDppN<3>(er);
        spe0 = er[0] * delx; spe1 = er[1] * delx; eho = er[2] * delx * 0.5f;
      }
    }
    __syncthreads();   // B2 — next conv may read nw*/p* safely

    // ===== final iteration: ekin/epot via 6-conv pass =====
    if (last) {
      if (isK) {
        float bA0[4] = {0,0,0,0}, bA1[4] = {0,0,0,0};
#pragma unroll
        for (int b = 0; b < NBLK; ++b) {
          const int j0 = jg + 4 * b;
          const float4 n0q = *(const float4*)&nw0[j0];
          const float4 n1q = *(const float4*)&nw1[j0];
          const float4 kh = cw[15 - b], kl = cw[14 - b];
          const float ck[8] = {kl.x, kl.y, kl.z, kl.w, kh.x, kh.y, kh.z, kh.w};
          const float xn0[4] = {n0q.x, n0q.y, n0q.z, n0q.w};
          const float xn1[4] = {n1q.x, n1q.y, n1q.z, n1q.w};
#pragma unroll
          for (int s = 0; s < 4; ++s) {
#pragma unroll
            for (int r = 0; r < 4; ++r) {
              const int c = 4 + r - s;
              bA0[r] = fmaf(xn0[s], ck[c], bA0[r]);          // kin@new0
              bA1[r] = fmaf(xn1[s], ck[c], bA1[r]);          // kin@new1
            }
          }
        }
        *(float4*)&sm.part[g][0][i0] = make_float4(bA0[0], bA0[1], bA0[2], bA0[3]);
        *(float4*)&sm.part[g][1][i0] = make_float4(bA1[0], bA1[1], bA1[2], bA1[3]);
      } else {
        float bV[4][4] = {};
#pragma unroll
        for (int b = 0; b < NBLK; ++b) {
          const int j0 = jg + 4 * b;
          const float4 o0q = *(const float4*)&wf0[j0];
          const float4 o1q = *(const float4*)&wf1[j0];
          const float4 n0q = *(const float4*)&nw0[j0];
          const float4 n1q = *(const float4*)&nw1[j0];
          const float4 vh = cw[15 - b], vl = cw[14 - b];
          const float cv[8] = {vl.x, vl.y, vl.z, vl.w, vh.x, vh.y, vh.z, vh.w};
          const float xo0[4] = {o0q.x, o0q.y, o0q.z, o0q.w};
          const float xo1[4] = {o1q.x, o1q.y, o1q.z, o1q.w};
          const float xn0[4] = {n0q.x, n0q.y, n0q.z, n0q.w};
          const float xn1[4] = {n1q.x, n1q.y, n1q.z, n1q.w};
#pragma unroll
          for (int s = 0; s < 4; ++s) {
            const float pr00 = xo0[s] * xn0[s];
            const float pr10 = xo1[s] * xn0[s];
            const float pr01 = xo0[s] * xn1[s];
            const float pr11 = xo1[s] * xn1[s];
#pragma unroll
            for (int r = 0; r < 4; ++r) {
              const int c = 4 + r - s;
              bV[0][r] = fmaf(pr00, cv[c], bV[0][r]);        // V@(wf0*new0)
              bV[1][r] = fmaf(pr10, cv[c], bV[1][r]);        // V@(wf1*new0)
              bV[2][r] = fmaf(pr01, cv[c], bV[2][r]);        // V@(wf0*new1)
              bV[3][r] = fmaf(pr11, cv[c], bV[3][r]);        // V@(wf1*new1)
            }
          }
        }
#pragma unroll
        for (int c2 = 0; c2 < 4; ++c2)
          *(float4*)&sm.part[g][2 + c2][i0] =
              make_float4(bV[c2][0], bV[c2][1], bV[c2][2], bV[c2][3]);
      }
      __syncthreads();

      if (wv == 0) {
        float rd[6][4] = {};
#pragma unroll
        for (int gg = 0; gg < 4; ++gg) {
#pragma unroll
          for (int c = 0; c < 6; ++c) {
            const float4 A = *(const float4*)&sm.part[gg][c][i0];
            rd[c][0] += A.x; rd[c][1] += A.y; rd[c][2] += A.z; rd[c][3] += A.w;
          }
        }
        float er[2] = {0, 0};                          // ekin, epot integrands
#pragma unroll
        for (int r = 0; r < 4; ++r) {
          // pads contribute 0: w0=w1=new0=new1=0 there
          const float um0 = -delx * (w0[r] * rd[2][r] + w1[r] * rd[3][r]) + Ut[r] * new0[r];
          const float um1 = -delx * (w0[r] * rd[4][r] + w1[r] * rd[5][r]) + Ut[r] * new1[r];
          er[0] += new0[r] * rd[0][r] + new1[r] * rd[1][r];
          er[1] += new0[r] * um0 + new1[r] * um1;
        }
        waveSumDppN<2>(er);
        const float ekin = er[0] * delx, epot = er[1] * delx;
        if (l == 0) {
          const float esum    = spe0 + spe1;
          const float enerhfp = 0.5f * (esum + ekin) + eho;
          const float epot0hf = epot - 2.f * eho;
          const float enerhf  = esum - 0.5f * epot0hf;
          out[0] = enerhf; out[1] = enerhfp; out[2] = ekin;
          out[3] = eho;    out[4] = epot0hf; out[5] = esum;
        }
      }
    }
    cur ^= 1;
  }
}

extern "C" void kernel_launch(void* const* d_in, const int* in_sizes, int n_in,
                              void* d_out, int out_size, void* d_ws, size_t ws_size,
                              hipStream_t stream) {
  const float* wfy0 = (const float*)d_in[0];
  const float* kin  = (const float*)d_in[1];
  const float* vnt  = (const float*)d_in[2];
  const float* uho  = (const float*)d_in[3];
  const float* delx = (const float*)d_in[4];
  const float* pfac = (const float*)d_in[5];
  const int*   itm  = (const int*)d_in[6];
  hipLaunchKernelGGL(hf_kernel, dim3(1), dim3(NTH), 0, stream,
                     wfy0, kin, vnt, uho, delx, pfac, itm, (float*)d_out);
}